// Round 1
// baseline (111.058 us; speedup 1.0000x reference)
//
#include <hip/hip_runtime.h>

// Problem constants (from reference): B=4096, K=32, U=32768, V=100000, D=128
#define B_ROWS 4096
#define KNZ 32
#define U_COLS 32768
#define D_DIM 128
#define ROWS_PER_BLOCK 8

// Kernel 1: per-row dedupe + column-degree histogram.
// One thread per row: load its 32 cols, O(K^2) dedupe, atomicAdd col_deg for
// each distinct col. row_deg is recomputed cheaply in kernel 2 (no need to store).
__global__ __launch_bounds__(256) void col_deg_kernel(
    const int* __restrict__ neigh, int* __restrict__ col_deg)
{
    int b = blockIdx.x * blockDim.x + threadIdx.x;
    if (b >= B_ROWS) return;
    int c[KNZ];
#pragma unroll
    for (int k = 0; k < KNZ; ++k) c[k] = neigh[b * KNZ + k];
#pragma unroll
    for (int k = 0; k < KNZ; ++k) {
        bool dup = false;
#pragma unroll
        for (int j = 0; j < KNZ; ++j) {
            if (j < k) dup = dup || (c[j] == c[k]);
        }
        if (!dup) atomicAdd(&col_deg[c[k]], 1);
    }
}

// Kernel 2: aggregate. 8 rows per 256-thread block; 32 threads per row,
// each thread owns one float4 slice of D=128.
__global__ __launch_bounds__(256) void aggregate_kernel(
    const int* __restrict__ neigh, const int* __restrict__ uids,
    const float* __restrict__ embed, const int* __restrict__ col_deg,
    float* __restrict__ out)
{
    __shared__ int   s_cols[ROWS_PER_BLOCK][KNZ];
    __shared__ int   s_eidx[ROWS_PER_BLOCK][KNZ];
    __shared__ float s_w[ROWS_PER_BLOCK][KNZ];
    __shared__ float s_rs[ROWS_PER_BLOCK];

    const int r    = threadIdx.x >> 5;   // row-group within block: 0..7
    const int lane = threadIdx.x & 31;   // 0..31 within row-group
    const int b    = blockIdx.x * ROWS_PER_BLOCK + r;

    // Stage this row's 32 cols to LDS.
    const int c = neigh[b * KNZ + lane];
    s_cols[r][lane] = c;
    __syncthreads();

    // Dedupe: keep iff no earlier slot in this row has the same col.
    bool keep = true;
    for (int j = 0; j < lane; ++j) keep = keep && (s_cols[r][j] != c);

    // row_deg = popcount of keep bits within this 32-thread group.
    // All 256 threads are active here, so ballot covers the full 64-lane wave;
    // extract the half belonging to this group.
    unsigned long long bm = __ballot(keep);
    unsigned int half = (threadIdx.x & 32) ? (unsigned int)(bm >> 32)
                                           : (unsigned int)(bm & 0xffffffffULL);
    int row_deg = __popc(half);

    // Per-col weight (0 for duplicate slots) and embed row index.
    s_w[r][lane]    = keep ? rsqrtf((float)col_deg[c]) : 0.0f;
    s_eidx[r][lane] = uids[c];
    if (lane == 0) s_rs[r] = rsqrtf((float)row_deg);
    __syncthreads();

    // Gather-accumulate: 32 weighted float4 gathers from the embed table.
    const float4* ev = (const float4*)embed;  // D=128 floats = 32 float4 per row
    float4 acc = make_float4(0.f, 0.f, 0.f, 0.f);
#pragma unroll 8
    for (int j = 0; j < KNZ; ++j) {
        const float w = s_w[r][j];
        const long long idx = (long long)s_eidx[r][j] * (D_DIM / 4) + lane;
        const float4 e = ev[idx];
        acc.x += w * e.x;
        acc.y += w * e.y;
        acc.z += w * e.z;
        acc.w += w * e.w;
    }
    const float rs = s_rs[r];
    float4 o = make_float4(acc.x * rs, acc.y * rs, acc.z * rs, acc.w * rs);
    ((float4*)out)[(long long)b * (D_DIM / 4) + lane] = o;
}

extern "C" void kernel_launch(void* const* d_in, const int* in_sizes, int n_in,
                              void* d_out, int out_size, void* d_ws, size_t ws_size,
                              hipStream_t stream) {
    const int*   neigh = (const int*)d_in[0];    // [B, K] int32
    const int*   uids  = (const int*)d_in[1];    // [U] int32
    const float* embed = (const float*)d_in[2];  // [V, D] float32
    float*       out   = (float*)d_out;          // [B, D] float32
    int*         col_deg = (int*)d_ws;           // [U] int32 scratch

    // d_ws is poisoned 0xAA before every timed launch — re-zero every call.
    hipMemsetAsync(col_deg, 0, U_COLS * sizeof(int), stream);

    col_deg_kernel<<<B_ROWS / 256, 256, 0, stream>>>(neigh, col_deg);

    aggregate_kernel<<<B_ROWS / ROWS_PER_BLOCK, 256, 0, stream>>>(
        neigh, uids, embed, col_deg, out);
}